// Round 7
// baseline (606.259 us; speedup 1.0000x reference)
//
#include <hip/hip_runtime.h>

#define DIM 128
#define NCB 8
#define KSZ 2048
#define BATCH 16
#define TOK 2048
#define NTOK (BATCH * TOK)            // 32768
#define NELEM (BATCH * DIM * TOK)     // 4194304
#define T_TILE 128                    // tokens per block
#define NTHR 512                      // 8 waves
#define CHUNK 32                      // codes per chunk per group
#define NCHUNK 16                     // chunks per group per stage
#define GCODES 512                    // codes per group (4 groups)

typedef float f32x4 __attribute__((ext_vector_type(4)));
typedef _Float16 f16x8 __attribute__((ext_vector_type(8)));

// ---------------------------------------------------------------------------
// prep: codebooks -> fp16 plane (RNE cast)
// ---------------------------------------------------------------------------
__global__ void rvq_prep_f16(const float* __restrict__ cbs,
                             _Float16* __restrict__ chf) {
    int i = blockIdx.x * 256 + threadIdx.x;
    chf[i] = (_Float16)cbs[i];
}

// ---------------------------------------------------------------------------
// exact fp32 cnorm (round-1 formula) + zero loss accumulator
// ---------------------------------------------------------------------------
__global__ void rvq_cnorm(const float* __restrict__ cbs,
                          float* __restrict__ cnorm,
                          float* __restrict__ loss_acc) {
    if (blockIdx.x == 0 && threadIdx.x == 0) *loss_acc = 0.0f;
    int k = blockIdx.x * 256 + threadIdx.x;
    const float4* row = (const float4*)(cbs + (size_t)k * DIM);
    float s = 0.0f;
#pragma unroll
    for (int i = 0; i < DIM / 4; ++i) {
        float4 v = row[i];
        s += v.x * v.x + v.y * v.y + v.z * v.z + v.w * v.w;
    }
    cnorm[k] = s;
}

// ---------------------------------------------------------------------------
// fused RVQ. 8 waves = 4 groups x 2 subs. Group g scans codes [g*512,+512)
// in 16 chunks of 32; sub splits tokens. B fragments are loaded DIRECTLY
// from global (L2-resident fp16 codebook) into a register double-buffer —
// no LDS staging, no barriers in the chunk loop (3 barriers/stage total).
// Per-lane top-2 keys per 32-code class with (chunk,nt,col) in 9 low
// mantissa bits; per-group top-4 merge -> 16 exact fp32 rescores/token.
// grid 256 blocks (1/CU), 512 threads (2 waves/SIMD).
// ---------------------------------------------------------------------------
__global__ __launch_bounds__(NTHR, 2) void rvq_fused(
        const float* __restrict__ x,           // (B, D, T)
        const float* __restrict__ cbs,         // (NCB, KSZ, DIM) fp32
        const _Float16* __restrict__ chf,      // fp16 codebooks
        const float* __restrict__ cng,         // (NCB*KSZ) exact cnorm
        float* __restrict__ out,               // (B, D, T)
        float* __restrict__ codes,             // (B, NCB, T) as float
        float* __restrict__ loss_acc) {
    __shared__ float res_lds[T_TILE][DIM + 4];   // 67584 B
    __shared__ float cand[T_TILE * 132];         // 67584 B (stride 132 floats)
    __shared__ float cn_lds[KSZ];                // 8192 B   => 143360 B total

    const int tid   = threadIdx.x;
    const int lane  = tid & 63;
    const int wv    = __builtin_amdgcn_readfirstlane(tid >> 6);  // 0..7
    const int col16 = lane & 15;
    const int quad  = lane >> 4;
    const int g     = wv >> 1;        // group 0..3
    const int sub   = wv & 1;         // wave within group (token half)

    const int token0 = blockIdx.x * T_TILE;
    const int b      = token0 >> 11;
    const int t_in_b = token0 & (TOK - 1);

    // ---- init: x[b][d][t0..] -> res_lds[t][d] ----
    {
        const float* xb = x + (size_t)b * DIM * TOK + t_in_b;
#pragma unroll
        for (int it = 0; it < 8; ++it) {
            int idx = it * NTHR + tid;           // 0..4095
            int d  = idx >> 5;
            int t4 = (idx & 31) * 4;
            float4 v = *(const float4*)(xb + (size_t)d * TOK + t4);
            res_lds[t4 + 0][d] = v.x;
            res_lds[t4 + 1][d] = v.y;
            res_lds[t4 + 2][d] = v.z;
            res_lds[t4 + 3][d] = v.w;
        }
    }
    __syncthreads();

    float my_loss = 0.0f;
    const float INFV = __builtin_inff();

#define LOADB(dst)                                                             \
    {                                                                          \
        _Pragma("unroll")                                                      \
        for (int dc = 0; dc < 4; ++dc) {                                       \
            dst[dc]     = *(const f16x8*)(p0 + dc * 32);                       \
            dst[4 + dc] = *(const f16x8*)(p1 + dc * 32);                       \
        }                                                                      \
    }

#define COMPUTE(bX)                                                            \
    {                                                                          \
        _Pragma("unroll")                                                      \
        for (int mt = 0; mt < 4; ++mt) {                                       \
            acc[mt][0] = (f32x4){0.f, 0.f, 0.f, 0.f};                          \
            acc[mt][1] = (f32x4){0.f, 0.f, 0.f, 0.f};                          \
        }                                                                      \
        _Pragma("unroll")                                                      \
        for (int dc = 0; dc < 4; ++dc) {                                       \
            _Pragma("unroll")                                                  \
            for (int mt = 0; mt < 4; ++mt) {                                   \
                acc[mt][0] = __builtin_amdgcn_mfma_f32_16x16x32_f16(           \
                    ah[mt][dc], bX[dc], acc[mt][0], 0, 0, 0);                  \
                acc[mt][1] = __builtin_amdgcn_mfma_f32_16x16x32_f16(           \
                    ah[mt][dc], bX[4 + dc], acc[mt][1], 0, 0, 0);              \
            }                                                                  \
        }                                                                      \
    }

// key = approx score with low 9 mantissa bits = (chunk<<5)|(nt<<4)|col16.
// Insert BOTH nt scores into per-class (slot,col16) top-2.
#define FOLD(cc)                                                               \
    {                                                                          \
        float cn0 = cn_lds[g * GCODES + (cc) * CHUNK + col16];                 \
        float cn1 = cn_lds[g * GCODES + (cc) * CHUNK + 16 + col16];            \
        unsigned em0 = ((unsigned)(cc) << 5) | (unsigned)col16;                \
        unsigned em1 = em0 | 16u;                                              \
        _Pragma("unroll")                                                      \
        for (int mt = 0; mt < 4; ++mt) {                                       \
            _Pragma("unroll")                                                  \
            for (int r = 0; r < 4; ++r) {                                      \
                int sl = mt * 4 + r;                                           \
                float p0s = fmaf(-2.0f, acc[mt][0][r], cn0);                   \
                float p1s = fmaf(-2.0f, acc[mt][1][r], cn1);                   \
                float q0 = __uint_as_float(                                    \
                    (__float_as_uint(p0s) & 0xFFFFFE00u) | em0);               \
                float q1 = __uint_as_float(                                    \
                    (__float_as_uint(p1s) & 0xFFFFFE00u) | em1);               \
                k2[sl] = fminf(k2[sl], fmaxf(k1[sl], q0));                     \
                k1[sl] = fminf(k1[sl], q0);                                    \
                k2[sl] = fminf(k2[sl], fmaxf(k1[sl], q1));                     \
                k1[sl] = fminf(k1[sl], q1);                                    \
            }                                                                  \
        }                                                                      \
    }

#pragma unroll 1
    for (int s = 0; s < NCB; ++s) {
        const _Float16* __restrict__ ch_s = chf + (size_t)s * KSZ * DIM;
        const float* __restrict__ cb_s = cbs + (size_t)s * KSZ * DIM;
        const float* __restrict__ cn_s = cng + (size_t)s * KSZ;

        // ---- issue chunk-0 B loads early (pure global, no LDS dep) ----
        const _Float16* p0 = ch_s + (size_t)(g * GCODES + col16) * DIM + quad * 8;
        const _Float16* p1 = p0 + 16 * DIM;
        f16x8 bA[8], bB[8];
        LOADB(bA);

        // ---- stage cnorm into LDS (readers wait for barrier below) ----
        *(float4*)&cn_lds[tid * 4] = *(const float4*)(cn_s + tid * 4);

        // ---- A fragments (fp16) from LDS residual; wave owns 64 tokens ----
        f16x8 ah[4][4];
#pragma unroll
        for (int mt = 0; mt < 4; ++mt) {
#pragma unroll
            for (int dc = 0; dc < 4; ++dc) {
                int t  = sub * 64 + mt * 16 + col16;
                int d0 = dc * 32 + quad * 8;
                float4 u = *(const float4*)&res_lds[t][d0];
                float4 w = *(const float4*)&res_lds[t][d0 + 4];
                f16x8 hv;
                hv[0] = (_Float16)u.x; hv[1] = (_Float16)u.y;
                hv[2] = (_Float16)u.z; hv[3] = (_Float16)u.w;
                hv[4] = (_Float16)w.x; hv[5] = (_Float16)w.y;
                hv[6] = (_Float16)w.z; hv[7] = (_Float16)w.w;
                ah[mt][dc] = hv;
            }
        }

        float k1[16], k2[16];
#pragma unroll
        for (int sl = 0; sl < 16; ++sl) { k1[sl] = INFV; k2[sl] = INFV; }

        __syncthreads();   // B1: cn_lds ready (A-build already done)

        // ---- barrier-free chunk loop, register-double-buffered B ----
        f32x4 acc[4][2];
#pragma unroll 1
        for (int c = 0; c < NCHUNK; c += 2) {
            p0 += CHUNK * DIM; p1 += CHUNK * DIM;
            LOADB(bB);                       // chunk c+1 in flight
            COMPUTE(bA);
            FOLD(c);
            if (c + 2 < NCHUNK) {
                p0 += CHUNK * DIM; p1 += CHUNK * DIM;
                LOADB(bA);                   // chunk c+2 in flight
            }
            COMPUTE(bB);
            FOLD(c + 1);
        }

        // ---- publish per-lane top-2 keys ----
#pragma unroll
        for (int mt = 0; mt < 4; ++mt) {
#pragma unroll
            for (int r = 0; r < 4; ++r) {
                int t = sub * 64 + mt * 16 + quad * 4 + r;
                int sl = mt * 4 + r;
                float2 pr; pr.x = k1[sl]; pr.y = k2[sl];
                *(float2*)&cand[t * 132 + g * 32 + col16 * 2] = pr;
            }
        }
        __syncthreads();   // B2: cand ready

        // ---- merge: per-group top-4 of 32 keys (identity in low bits) ----
        {
            const int t  = tid >> 2;
            const int gg = tid & 3;
            float bk0 = INFV, bk1 = INFV, bk2 = INFV, bk3 = INFV;
            const float* base = &cand[t * 132 + gg * 32];
#pragma unroll
            for (int j = 0; j < 8; ++j) {
                float4 v4 = *(const float4*)(base + j * 4);
                float vv[4] = {v4.x, v4.y, v4.z, v4.w};
#pragma unroll
                for (int e = 0; e < 4; ++e) {
                    float v = vv[e];
                    float M0 = fmaxf(bk0, v);  bk0 = fminf(bk0, v);
                    float M1 = fmaxf(bk1, M0); bk1 = fminf(bk1, M0);
                    float M2 = fmaxf(bk2, M1); bk2 = fminf(bk2, M1);
                    bk3 = fminf(bk3, M2);
                }
            }
            int cds[4];
            cds[0] = gg * GCODES + (int)(__float_as_uint(bk0) & 0x1FFu);
            cds[1] = gg * GCODES + (int)(__float_as_uint(bk1) & 0x1FFu);
            cds[2] = gg * GCODES + (int)(__float_as_uint(bk2) & 0x1FFu);
            cds[3] = gg * GCODES + (int)(__float_as_uint(bk3) & 0x1FFu);

            // exact fp32 rescore of 4 candidates (round-1 association)
            const float* q1p = cb_s + (size_t)cds[0] * DIM;
            const float* q2p = cb_s + (size_t)cds[1] * DIM;
            const float* q3p = cb_s + (size_t)cds[2] * DIM;
            const float* q4p = cb_s + (size_t)cds[3] * DIM;
            float n0 = 0, n1 = 0, n2 = 0, n3 = 0;
            float a[4][4];
#pragma unroll
            for (int jj = 0; jj < 4; ++jj)
#pragma unroll
                for (int e = 0; e < 4; ++e) a[jj][e] = 0.0f;
#pragma unroll 8
            for (int d4 = 0; d4 < DIM / 4; ++d4) {
                float4 r4 = *(const float4*)&res_lds[t][d4 * 4];
                n0 = fmaf(r4.x, r4.x, n0); n1 = fmaf(r4.y, r4.y, n1);
                n2 = fmaf(r4.z, r4.z, n2); n3 = fmaf(r4.w, r4.w, n3);
                float4 q0 = *(const float4*)(q1p + d4 * 4);
                a[0][0] = fmaf(r4.x, q0.x, a[0][0]);
                a[0][1] = fmaf(r4.y, q0.y, a[0][1]);
                a[0][2] = fmaf(r4.z, q0.z, a[0][2]);
                a[0][3] = fmaf(r4.w, q0.w, a[0][3]);
                float4 q1 = *(const float4*)(q2p + d4 * 4);
                a[1][0] = fmaf(r4.x, q1.x, a[1][0]);
                a[1][1] = fmaf(r4.y, q1.y, a[1][1]);
                a[1][2] = fmaf(r4.z, q1.z, a[1][2]);
                a[1][3] = fmaf(r4.w, q1.w, a[1][3]);
                float4 q2 = *(const float4*)(q3p + d4 * 4);
                a[2][0] = fmaf(r4.x, q2.x, a[2][0]);
                a[2][1] = fmaf(r4.y, q2.y, a[2][1]);
                a[2][2] = fmaf(r4.z, q2.z, a[2][2]);
                a[2][3] = fmaf(r4.w, q2.w, a[2][3]);
                float4 q3 = *(const float4*)(q4p + d4 * 4);
                a[3][0] = fmaf(r4.x, q3.x, a[3][0]);
                a[3][1] = fmaf(r4.y, q3.y, a[3][1]);
                a[3][2] = fmaf(r4.z, q3.z, a[3][2]);
                a[3][3] = fmaf(r4.w, q3.w, a[3][3]);
            }
            float rn = (n0 + n1) + (n2 + n3);
            float bd = INFV; int bc = 0x7FFFFFFF;
#pragma unroll
            for (int jj = 0; jj < 4; ++jj) {
                float dot = (a[jj][0] + a[jj][1]) + (a[jj][2] + a[jj][3]);
                float dist = fmaf(-2.0f, dot, rn) + cn_s[cds[jj]];
                if (dist < bd || (dist == bd && cds[jj] < bc)) {
                    bd = dist; bc = cds[jj];
                }
            }
#pragma unroll
            for (int mk = 1; mk <= 2; mk <<= 1) {
                float od = __shfl_xor(bd, mk, 64);
                int   oc = __shfl_xor(bc, mk, 64);
                if (od < bd || (od == bd && oc < bc)) { bd = od; bc = oc; }
            }
            if (gg == 0)
                codes[(size_t)b * (NCB * TOK) + (size_t)s * TOK + t_in_b + t] =
                    (float)bc;
            // update my 32-dim slice of the token's residual + loss partial
            const float* qrow = cb_s + (size_t)bc * DIM;
            float lp = 0.0f;
#pragma unroll
            for (int d4 = 0; d4 < 8; ++d4) {
                int d = gg * 32 + d4 * 4;
                float4 r4 = *(const float4*)&res_lds[t][d];
                float4 q4 = *(const float4*)(qrow + d);
                float4 nr;
                nr.x = r4.x - q4.x; nr.y = r4.y - q4.y;
                nr.z = r4.z - q4.z; nr.w = r4.w - q4.w;
                *(float4*)&res_lds[t][d] = nr;
                lp += nr.x * nr.x + nr.y * nr.y + nr.z * nr.z + nr.w * nr.w;
            }
            my_loss += lp;
        }
        __syncthreads();   // B3: res_lds updated for next stage
    }

    // ---- epilogue: out[b][d][t] = x - residual ----
    {
        const float* xb = x + (size_t)b * DIM * TOK + t_in_b;
        float* ob = out + (size_t)b * DIM * TOK + t_in_b;
#pragma unroll
        for (int it = 0; it < 8; ++it) {
            int idx = it * NTHR + tid;
            int d  = idx >> 5;
            int t4 = (idx & 31) * 4;
            float4 v = *(const float4*)(xb + (size_t)d * TOK + t4);
            float4 o;
            o.x = v.x - res_lds[t4 + 0][d];
            o.y = v.y - res_lds[t4 + 1][d];
            o.z = v.z - res_lds[t4 + 2][d];
            o.w = v.w - res_lds[t4 + 3][d];
            *(float4*)(ob + (size_t)d * TOK + t4) = o;
        }
    }

    // ---- loss reduction ----
#pragma unroll
    for (int off = 32; off > 0; off >>= 1)
        my_loss += __shfl_down(my_loss, off, 64);
    if (lane == 0) atomicAdd(loss_acc, my_loss);
}

// ---------------------------------------------------------------------------
__global__ void rvq_loss_fin(const float* __restrict__ loss_acc,
                             float* __restrict__ loss_out) {
    *loss_out = *loss_acc * (1.0f / (float)NELEM);
}

// ---------------------------------------------------------------------------
extern "C" void kernel_launch(void* const* d_in, const int* in_sizes, int n_in,
                              void* d_out, int out_size, void* d_ws, size_t ws_size,
                              hipStream_t stream) {
    const float* x   = (const float*)d_in[0];   // (B, D, T)
    const float* cbs = (const float*)d_in[1];   // (NCB, KSZ, DIM)

    float* out      = (float*)d_out;
    float* codes    = out + NELEM;
    float* loss_out = out + NELEM + (size_t)BATCH * NCB * TOK;

    float* wsf      = (float*)d_ws;
    float* loss_acc = wsf;
    _Float16* chf   = (_Float16*)(wsf + 256);
    float* cng      = (float*)(chf + (size_t)NCB * KSZ * DIM);

    hipLaunchKernelGGL(rvq_prep_f16, dim3((NCB * KSZ * DIM) / 256), dim3(256),
                       0, stream, cbs, chf);
    hipLaunchKernelGGL(rvq_cnorm, dim3((NCB * KSZ) / 256), dim3(256), 0, stream,
                       cbs, cng, loss_acc);
    hipLaunchKernelGGL(rvq_fused, dim3(NTOK / T_TILE), dim3(NTHR), 0, stream,
                       x, cbs, chf, cng, out, codes, loss_acc);
    hipLaunchKernelGGL(rvq_loss_fin, dim3(1), dim3(1), 0, stream,
                       loss_acc, loss_out);
}

// Round 8
// 571.465 us; speedup vs baseline: 1.0609x; 1.0609x over previous
//
#include <hip/hip_runtime.h>

#define DIM 128
#define NCB 8
#define KSZ 2048
#define BATCH 16
#define TOK 2048
#define NTOK (BATCH * TOK)            // 32768
#define NELEM (BATCH * DIM * TOK)     // 4194304
#define T_TILE 64                     // tokens per block
#define NTHR 256                      // 4 waves
#define CHUNK 32                      // codes per chunk per group
#define NCHUNK 16                     // chunks per group per stage
#define GCODES 512                    // codes per group (4 groups = 4 waves)

typedef float f32x4 __attribute__((ext_vector_type(4)));
typedef _Float16 f16x8 __attribute__((ext_vector_type(8)));

// ---------------------------------------------------------------------------
// prep: codebooks -> fp16 plane (RNE cast)
// ---------------------------------------------------------------------------
__global__ void rvq_prep_f16(const float* __restrict__ cbs,
                             _Float16* __restrict__ chf) {
    int i = blockIdx.x * 256 + threadIdx.x;
    chf[i] = (_Float16)cbs[i];
}

// ---------------------------------------------------------------------------
// exact fp32 cnorm (round-1 formula) + zero loss accumulator
// ---------------------------------------------------------------------------
__global__ void rvq_cnorm(const float* __restrict__ cbs,
                          float* __restrict__ cnorm,
                          float* __restrict__ loss_acc) {
    if (blockIdx.x == 0 && threadIdx.x == 0) *loss_acc = 0.0f;
    int k = blockIdx.x * 256 + threadIdx.x;
    const float4* row = (const float4*)(cbs + (size_t)k * DIM);
    float s = 0.0f;
#pragma unroll
    for (int i = 0; i < DIM / 4; ++i) {
        float4 v = row[i];
        s += v.x * v.x + v.y * v.y + v.z * v.z + v.w * v.w;
    }
    cnorm[k] = s;
}

// ---------------------------------------------------------------------------
// fused RVQ. 4 waves/block; wave = group g scans codes [g*512,+512) in 16
// chunks of 32 over all 64 tokens (mt=4, nt=2; 32 MFMA per 8 B-loads from
// the L2-resident fp16 codebook, register double-buffered, no barriers in
// the chunk loop). Per-lane top-2 keys per 32-code class with
// (chunk,nt,col) in 9 low mantissa bits; per-group top-4 merge -> 16
// candidates/token rescored exactly in fp32 with dimension-quartered
// COALESCED gathers + quartet shuffle-combine.
// grid 512 blocks (2/CU for phase overlap), 256 threads (1 wave/SIMD x 2).
// ---------------------------------------------------------------------------
__global__ __launch_bounds__(NTHR, 2) void rvq_fused(
        const float* __restrict__ x,           // (B, D, T)
        const float* __restrict__ cbs,         // (NCB, KSZ, DIM) fp32
        const _Float16* __restrict__ chf,      // fp16 codebooks
        const float* __restrict__ cng,         // (NCB*KSZ) exact cnorm
        float* __restrict__ out,               // (B, D, T)
        float* __restrict__ codes,             // (B, NCB, T) as float
        float* __restrict__ loss_acc) {
    __shared__ float res_lds[T_TILE][DIM + 4];   // 33792 B
    __shared__ float cand[T_TILE * 132];         // 33792 B
    __shared__ float cn_lds[KSZ];                // 8192 B
    __shared__ int   best16s[T_TILE][16];        // 4096 B => 79872 B total

    const int tid   = threadIdx.x;
    const int lane  = tid & 63;
    const int g     = __builtin_amdgcn_readfirstlane(tid >> 6);  // 0..3
    const int col16 = lane & 15;
    const int quad  = lane >> 4;

    const int token0 = blockIdx.x * T_TILE;
    const int b      = token0 >> 11;
    const int t_in_b = token0 & (TOK - 1);

    // ---- init: x[b][d][t0..] -> res_lds[t][d] ----
    {
        const float* xb = x + (size_t)b * DIM * TOK + t_in_b;
#pragma unroll
        for (int it = 0; it < 8; ++it) {
            int idx = it * NTHR + tid;           // 0..2047
            int d  = idx >> 4;
            int t4 = (idx & 15) * 4;
            float4 v = *(const float4*)(xb + (size_t)d * TOK + t4);
            res_lds[t4 + 0][d] = v.x;
            res_lds[t4 + 1][d] = v.y;
            res_lds[t4 + 2][d] = v.z;
            res_lds[t4 + 3][d] = v.w;
        }
    }
    __syncthreads();

    float my_loss = 0.0f;
    const float INFV = __builtin_inff();

#define LOADB(dst)                                                             \
    {                                                                          \
        _Pragma("unroll")                                                      \
        for (int dc = 0; dc < 4; ++dc) {                                       \
            dst[dc]     = *(const f16x8*)(p0 + dc * 32);                       \
            dst[4 + dc] = *(const f16x8*)(p1 + dc * 32);                       \
        }                                                                      \
    }

#define COMPUTE(bX)                                                            \
    {                                                                          \
        _Pragma("unroll")                                                      \
        for (int mt = 0; mt < 4; ++mt) {                                       \
            acc[mt][0] = (f32x4){0.f, 0.f, 0.f, 0.f};                          \
            acc[mt][1] = (f32x4){0.f, 0.f, 0.f, 0.f};                          \
        }                                                                      \
        _Pragma("unroll")                                                      \
        for (int dc = 0; dc < 4; ++dc) {                                       \
            _Pragma("unroll")                                                  \
            for (int mt = 0; mt < 4; ++mt) {                                   \
                acc[mt][0] = __builtin_amdgcn_mfma_f32_16x16x32_f16(           \
                    ah[mt][dc], bX[dc], acc[mt][0], 0, 0, 0);                  \
                acc[mt][1] = __builtin_amdgcn_mfma_f32_16x16x32_f16(           \
                    ah[mt][dc], bX[4 + dc], acc[mt][1], 0, 0, 0);              \
            }                                                                  \
        }                                                                      \
    }

// key = approx score with low 9 mantissa bits = (chunk<<5)|(nt<<4)|col16.
// Insert BOTH nt scores into the per-(slot,col16)-class top-2.
#define FOLD(cc)                                                               \
    {                                                                          \
        float cn0 = cn_lds[g * GCODES + (cc) * CHUNK + col16];                 \
        float cn1 = cn_lds[g * GCODES + (cc) * CHUNK + 16 + col16];            \
        unsigned em0 = ((unsigned)(cc) << 5) | (unsigned)col16;                \
        unsigned em1 = em0 | 16u;                                              \
        _Pragma("unroll")                                                      \
        for (int mt = 0; mt < 4; ++mt) {                                       \
            _Pragma("unroll")                                                  \
            for (int r = 0; r < 4; ++r) {                                      \
                int sl = mt * 4 + r;                                           \
                float p0s = fmaf(-2.0f, acc[mt][0][r], cn0);                   \
                float p1s = fmaf(-2.0f, acc[mt][1][r], cn1);                   \
                float q0 = __uint_as_float(                                    \
                    (__float_as_uint(p0s) & 0xFFFFFE00u) | em0);               \
                float q1 = __uint_as_float(                                    \
                    (__float_as_uint(p1s) & 0xFFFFFE00u) | em1);               \
                k2[sl] = fminf(k2[sl], fmaxf(k1[sl], q0));                     \
                k1[sl] = fminf(k1[sl], q0);                                    \
                k2[sl] = fminf(k2[sl], fmaxf(k1[sl], q1));                     \
                k1[sl] = fminf(k1[sl], q1);                                    \
            }                                                                  \
        }                                                                      \
    }

#pragma unroll 1
    for (int s = 0; s < NCB; ++s) {
        const _Float16* __restrict__ ch_s = chf + (size_t)s * KSZ * DIM;
        const float* __restrict__ cb_s = cbs + (size_t)s * KSZ * DIM;
        const float* __restrict__ cn_s = cng + (size_t)s * KSZ;

        // ---- issue chunk-0 B loads early ----
        const _Float16* p0 = ch_s + (size_t)(g * GCODES + col16) * DIM + quad * 8;
        const _Float16* p1 = p0 + 16 * DIM;
        f16x8 bA[8], bB[8];
        LOADB(bA);

        // ---- stage cnorm into LDS ----
#pragma unroll
        for (int i = 0; i < 2; ++i) {
            int idx = tid + i * NTHR;            // 0..511
            *(float4*)&cn_lds[idx * 4] = *(const float4*)(cn_s + idx * 4);
        }

        // ---- A fragments (fp16) from LDS residual; wave owns 64 tokens ----
        f16x8 ah[4][4];
#pragma unroll
        for (int mt = 0; mt < 4; ++mt) {
#pragma unroll
            for (int dc = 0; dc < 4; ++dc) {
                int t  = mt * 16 + col16;
                int d0 = dc * 32 + quad * 8;
                float4 u = *(const float4*)&res_lds[t][d0];
                float4 w = *(const float4*)&res_lds[t][d0 + 4];
                f16x8 hv;
                hv[0] = (_Float16)u.x; hv[1] = (_Float16)u.y;
                hv[2] = (_Float16)u.z; hv[3] = (_Float16)u.w;
                hv[4] = (_Float16)w.x; hv[5] = (_Float16)w.y;
                hv[6] = (_Float16)w.z; hv[7] = (_Float16)w.w;
                ah[mt][dc] = hv;
            }
        }

        float k1[16], k2[16];
#pragma unroll
        for (int sl = 0; sl < 16; ++sl) { k1[sl] = INFV; k2[sl] = INFV; }

        __syncthreads();   // B1: cn_lds ready; prev-stage cn readers done

        // ---- barrier-free chunk loop, register-double-buffered B ----
        f32x4 acc[4][2];
#pragma unroll 1
        for (int c = 0; c < NCHUNK; c += 2) {
            p0 += CHUNK * DIM; p1 += CHUNK * DIM;
            LOADB(bB);                       // chunk c+1 in flight
            COMPUTE(bA);
            FOLD(c);
            if (c + 2 < NCHUNK) {
                p0 += CHUNK * DIM; p1 += CHUNK * DIM;
                LOADB(bA);                   // chunk c+2 in flight
            }
            COMPUTE(bB);
            FOLD(c + 1);
        }

        // ---- publish per-lane top-2 keys ----
#pragma unroll
        for (int mt = 0; mt < 4; ++mt) {
#pragma unroll
            for (int r = 0; r < 4; ++r) {
                int t = mt * 16 + quad * 4 + r;
                int sl = mt * 4 + r;
                float2 pr; pr.x = k1[sl]; pr.y = k2[sl];
                *(float2*)&cand[t * 132 + g * 32 + col16 * 2] = pr;
            }
        }
        __syncthreads();   // B2: cand ready

        // ---- merge + COALESCED exact rescore + update ----
        {
            const int t  = tid >> 2;         // 0..63
            const int gg = tid & 3;
            // per-group top-4 of 32 keys (identity in low bits)
            float bk0 = INFV, bk1 = INFV, bk2 = INFV, bk3 = INFV;
            const float* base = &cand[t * 132 + gg * 32];
#pragma unroll
            for (int j = 0; j < 8; ++j) {
                float4 v4 = *(const float4*)(base + j * 4);
                float vv[4] = {v4.x, v4.y, v4.z, v4.w};
#pragma unroll
                for (int e = 0; e < 4; ++e) {
                    float v = vv[e];
                    float M0 = fmaxf(bk0, v);  bk0 = fminf(bk0, v);
                    float M1 = fmaxf(bk1, M0); bk1 = fminf(bk1, M0);
                    float M2 = fmaxf(bk2, M1); bk2 = fminf(bk2, M1);
                    bk3 = fminf(bk3, M2);
                }
            }
            best16s[t][gg * 4 + 0] = gg * GCODES + (int)(__float_as_uint(bk0) & 0x1FFu);
            best16s[t][gg * 4 + 1] = gg * GCODES + (int)(__float_as_uint(bk1) & 0x1FFu);
            best16s[t][gg * 4 + 2] = gg * GCODES + (int)(__float_as_uint(bk2) & 0x1FFu);
            best16s[t][gg * 4 + 3] = gg * GCODES + (int)(__float_as_uint(bk3) & 0x1FFu);
            // quartet lives in one wave: LDS write->read needs no barrier
            int cds16[16];
#pragma unroll
            for (int jj = 0; jj < 16; ++jj) cds16[jj] = best16s[t][jj];

            // my 32-dim residual slice -> registers (8 ds_read_b128)
            float4 rq[8];
#pragma unroll
            for (int d4 = 0; d4 < 8; ++d4)
                rq[d4] = *(const float4*)&res_lds[t][gg * 32 + d4 * 4];

            // rn partial + quartet combine
            float n0 = 0, n1 = 0, n2 = 0, n3 = 0;
#pragma unroll
            for (int d4 = 0; d4 < 8; ++d4) {
                n0 = fmaf(rq[d4].x, rq[d4].x, n0);
                n1 = fmaf(rq[d4].y, rq[d4].y, n1);
                n2 = fmaf(rq[d4].z, rq[d4].z, n2);
                n3 = fmaf(rq[d4].w, rq[d4].w, n3);
            }
            float rn = (n0 + n1) + (n2 + n3);
            rn += __shfl_xor(rn, 1, 64);
            rn += __shfl_xor(rn, 2, 64);

            // 16 candidates x my dim-quarter: coalesced rows (quartet spans
            // 128B of the same row per jj)
            float dist16[16];
#pragma unroll 4
            for (int jj = 0; jj < 16; ++jj) {
                const float* crow = cb_s + (size_t)cds16[jj] * DIM + gg * 32;
                float a0 = 0, a1 = 0, a2 = 0, a3 = 0;
#pragma unroll
                for (int d4 = 0; d4 < 8; ++d4) {
                    float4 q4 = *(const float4*)(crow + d4 * 4);
                    a0 = fmaf(rq[d4].x, q4.x, a0);
                    a1 = fmaf(rq[d4].y, q4.y, a1);
                    a2 = fmaf(rq[d4].z, q4.z, a2);
                    a3 = fmaf(rq[d4].w, q4.w, a3);
                }
                float pd = (a0 + a1) + (a2 + a3);
                pd += __shfl_xor(pd, 1, 64);
                pd += __shfl_xor(pd, 2, 64);
                dist16[jj] = fmaf(-2.0f, pd, rn) + cn_lds[cds16[jj]];
            }
            // argmin with first-index tie-break (all quartet threads agree)
            float bd = INFV; int bc = 0x7FFFFFFF;
#pragma unroll
            for (int jj = 0; jj < 16; ++jj) {
                if (dist16[jj] < bd || (dist16[jj] == bd && cds16[jj] < bc)) {
                    bd = dist16[jj]; bc = cds16[jj];
                }
            }
            if (gg == 0)
                codes[(size_t)b * (NCB * TOK) + (size_t)s * TOK + t_in_b + t] =
                    (float)bc;
            // update my 32-dim slice + loss partial
            const float* qrow = cb_s + (size_t)bc * DIM + gg * 32;
            float lp = 0.0f;
#pragma unroll
            for (int d4 = 0; d4 < 8; ++d4) {
                float4 q4 = *(const float4*)(qrow + d4 * 4);
                float4 nr;
                nr.x = rq[d4].x - q4.x; nr.y = rq[d4].y - q4.y;
                nr.z = rq[d4].z - q4.z; nr.w = rq[d4].w - q4.w;
                *(float4*)&res_lds[t][gg * 32 + d4 * 4] = nr;
                lp += nr.x * nr.x + nr.y * nr.y + nr.z * nr.z + nr.w * nr.w;
            }
            my_loss += lp;
        }
        __syncthreads();   // B3: res_lds updated for next stage
    }

    // ---- epilogue: out[b][d][t] = x - residual ----
    {
        const float* xb = x + (size_t)b * DIM * TOK + t_in_b;
        float* ob = out + (size_t)b * DIM * TOK + t_in_b;
#pragma unroll
        for (int it = 0; it < 8; ++it) {
            int idx = it * NTHR + tid;
            int d  = idx >> 4;
            int t4 = (idx & 15) * 4;
            float4 v = *(const float4*)(xb + (size_t)d * TOK + t4);
            float4 o;
            o.x = v.x - res_lds[t4 + 0][d];
            o.y = v.y - res_lds[t4 + 1][d];
            o.z = v.z - res_lds[t4 + 2][d];
            o.w = v.w - res_lds[t4 + 3][d];
            *(float4*)(ob + (size_t)d * TOK + t4) = o;
        }
    }

    // ---- loss reduction ----
#pragma unroll
    for (int off = 32; off > 0; off >>= 1)
        my_loss += __shfl_down(my_loss, off, 64);
    if (lane == 0) atomicAdd(loss_acc, my_loss);
}

// ---------------------------------------------------------------------------
__global__ void rvq_loss_fin(const float* __restrict__ loss_acc,
                             float* __restrict__ loss_out) {
    *loss_out = *loss_acc * (1.0f / (float)NELEM);
}

// ---------------------------------------------------------------------------
extern "C" void kernel_launch(void* const* d_in, const int* in_sizes, int n_in,
                              void* d_out, int out_size, void* d_ws, size_t ws_size,
                              hipStream_t stream) {
    const float* x   = (const float*)d_in[0];   // (B, D, T)
    const float* cbs = (const float*)d_in[1];   // (NCB, KSZ, DIM)

    float* out      = (float*)d_out;
    float* codes    = out + NELEM;
    float* loss_out = out + NELEM + (size_t)BATCH * NCB * TOK;

    float* wsf      = (float*)d_ws;
    float* loss_acc = wsf;
    _Float16* chf   = (_Float16*)(wsf + 256);
    float* cng      = (float*)(chf + (size_t)NCB * KSZ * DIM);

    hipLaunchKernelGGL(rvq_prep_f16, dim3((NCB * KSZ * DIM) / 256), dim3(256),
                       0, stream, cbs, chf);
    hipLaunchKernelGGL(rvq_cnorm, dim3((NCB * KSZ) / 256), dim3(256), 0, stream,
                       cbs, cng, loss_acc);
    hipLaunchKernelGGL(rvq_fused, dim3(NTOK / T_TILE), dim3(NTHR), 0, stream,
                       x, cbs, chf, cng, out, codes, loss_acc);
    hipLaunchKernelGGL(rvq_loss_fin, dim3(1), dim3(1), 0, stream,
                       loss_acc, loss_out);
}